// Round 1
// baseline (285.675 us; speedup 1.0000x reference)
//
#include <hip/hip_runtime.h>
#include <hip/hip_bf16.h>

#define B_   4
#define N_   2048
#define C_   1024
#define H_   16
#define D_   64
#define KVT  64
#define QBLK 64
#define SCALE 0.125f

typedef __attribute__((ext_vector_type(8))) short short8;
typedef __attribute__((ext_vector_type(4))) float f32x4;

__device__ __forceinline__ unsigned short f2bf(float x) {
    unsigned int u = __float_as_uint(x);
    u += 0x7FFFu + ((u >> 16) & 1u);   // round-to-nearest-even
    return (unsigned short)(u >> 16);
}

__global__ __launch_bounds__(256) void attn_fwd(
    const float* __restrict__ Q, const float* __restrict__ K,
    const float* __restrict__ V, float* __restrict__ O)
{
    // K tile [kv][d], V tile transposed [d][kv], P per-wave [qr][kv]; all bf16, XOR-swizzled
    __shared__ unsigned short klds[KVT * 64];
    __shared__ unsigned short vlds[64 * KVT];
    __shared__ unsigned short plds[4][16 * 64];

    // --- block decode with XCD-affinity swizzle: all 32 q-tiles of one head share L%8 ---
    int L = blockIdx.x;              // 0..2047
    int xcd = L & 7;
    int j = L >> 3;                  // 0..255
    int head_lin = xcd + 8 * (j >> 5);  // 0..63
    int qt = j & 31;                 // 0..31
    int b = head_lin >> 4;
    int h = head_lin & 15;

    const int tid  = threadIdx.x;
    const int wave = tid >> 6;
    const int lane = tid & 63;
    const int l16  = lane & 15;
    const int grp  = lane >> 4;

    const size_t head_off = (size_t)b * N_ * C_ + (size_t)h * D_;
    const float* qp = Q + head_off;
    const float* kp = K + head_off;
    const float* vp = V + head_off;
    float*       op = O + head_off;

    // --- load Q fragments (rows qt*64 + wave*16 + l16), fold in softmax scale ---
    const int qrow = qt * QBLK + wave * 16 + l16;
    short8 qa[2];
    {
        const float* qr = qp + (size_t)qrow * C_ + grp * 8;
        #pragma unroll
        for (int kk = 0; kk < 2; ++kk) {
            f32x4 x0 = *(const f32x4*)(qr + kk * 32);
            f32x4 x1 = *(const f32x4*)(qr + kk * 32 + 4);
            short8 a;
            #pragma unroll
            for (int i = 0; i < 4; ++i) {
                a[i]     = (short)f2bf(x0[i] * SCALE);
                a[i + 4] = (short)f2bf(x1[i] * SCALE);
            }
            qa[kk] = a;
        }
    }

    f32x4 o_acc[4] = {};             // 4 d-tiles of 16, rows grp*4+i
    float m_r[4], l_r[4];
    #pragma unroll
    for (int i = 0; i < 4; ++i) { m_r[i] = -1e30f; l_r[i] = 0.0f; }

    const int r_st = tid >> 2;       // staging row 0..63
    const int cb   = tid & 3;        // staging col block 0..3 (x16 floats)

    for (int t = 0; t < N_ / KVT; ++t) {
        const int kv0 = t * KVT;
        __syncthreads();
        // --- stage K tile: [kv][d] bf16, swizzled ---
        {
            const float* src = kp + (size_t)(kv0 + r_st) * C_ + cb * 16;
            f32x4 x0 = *(const f32x4*)(src);
            f32x4 x1 = *(const f32x4*)(src + 4);
            f32x4 x2 = *(const f32x4*)(src + 8);
            f32x4 x3 = *(const f32x4*)(src + 12);
            short8 p0, p1;
            #pragma unroll
            for (int i = 0; i < 4; ++i) {
                p0[i]     = (short)f2bf(x0[i]);
                p0[i + 4] = (short)f2bf(x1[i]);
                p1[i]     = (short)f2bf(x2[i]);
                p1[i + 4] = (short)f2bf(x3[i]);
            }
            const int base = r_st * 64;
            const int swz  = (r_st & 7) << 3;
            *(short8*)&klds[base + ((cb * 16)     ^ swz)] = p0;
            *(short8*)&klds[base + ((cb * 16 + 8) ^ swz)] = p1;
        }
        // --- stage V tile transposed: vlds[d][kv] bf16, swizzled per d-row ---
        {
            const float* src = vp + (size_t)(kv0 + r_st) * C_ + cb * 16;
            f32x4 y0 = *(const f32x4*)(src);
            f32x4 y1 = *(const f32x4*)(src + 4);
            f32x4 y2 = *(const f32x4*)(src + 8);
            f32x4 y3 = *(const f32x4*)(src + 12);
            #pragma unroll
            for (int i = 0; i < 4; ++i) {
                int d0 = cb * 16 + i;
                vlds[d0 * 64 + (r_st ^ ((d0 & 7) << 3))] = f2bf(y0[i]);
                int d1 = cb * 16 + 4 + i;
                vlds[d1 * 64 + (r_st ^ ((d1 & 7) << 3))] = f2bf(y1[i]);
                int d2 = cb * 16 + 8 + i;
                vlds[d2 * 64 + (r_st ^ ((d2 & 7) << 3))] = f2bf(y2[i]);
                int d3 = cb * 16 + 12 + i;
                vlds[d3 * 64 + (r_st ^ ((d3 & 7) << 3))] = f2bf(y3[i]);
            }
        }
        __syncthreads();

        // --- QK^T: S[16 x 64] per wave ---
        f32x4 s[4];
        #pragma unroll
        for (int ct = 0; ct < 4; ++ct) {
            const int krow = ct * 16 + l16;
            const int ksw  = (krow & 7) << 3;
            short8 b0 = *(const short8*)&klds[krow * 64 + ((grp * 8)      ^ ksw)];
            short8 b1 = *(const short8*)&klds[krow * 64 + ((32 + grp * 8) ^ ksw)];
            f32x4 acc = {};
            acc = __builtin_amdgcn_mfma_f32_16x16x32_bf16(qa[0], b0, acc, 0, 0, 0);
            acc = __builtin_amdgcn_mfma_f32_16x16x32_bf16(qa[1], b1, acc, 0, 0, 0);
            s[ct] = acc;
        }

        // --- online softmax (rows grp*4+i; reduce over 16 lanes of the group) ---
        float mnew[4], corr[4], rs[4];
        #pragma unroll
        for (int i = 0; i < 4; ++i) {
            float v0 = fmaxf(fmaxf(s[0][i], s[1][i]), fmaxf(s[2][i], s[3][i]));
            v0 = fmaxf(v0, __shfl_xor(v0, 1));
            v0 = fmaxf(v0, __shfl_xor(v0, 2));
            v0 = fmaxf(v0, __shfl_xor(v0, 4));
            v0 = fmaxf(v0, __shfl_xor(v0, 8));
            mnew[i] = fmaxf(m_r[i], v0);
            corr[i] = __expf(m_r[i] - mnew[i]);
            rs[i] = 0.0f;
        }
        unsigned short pb[4][4];
        #pragma unroll
        for (int ct = 0; ct < 4; ++ct) {
            #pragma unroll
            for (int i = 0; i < 4; ++i) {
                float p = __expf(s[ct][i] - mnew[i]);
                rs[i] += p;
                pb[ct][i] = f2bf(p);
            }
        }
        #pragma unroll
        for (int i = 0; i < 4; ++i) {
            float r = rs[i];
            r += __shfl_xor(r, 1);
            r += __shfl_xor(r, 2);
            r += __shfl_xor(r, 4);
            r += __shfl_xor(r, 8);
            l_r[i] = l_r[i] * corr[i] + r;
            m_r[i] = mnew[i];
            #pragma unroll
            for (int dt = 0; dt < 4; ++dt) o_acc[dt][i] *= corr[i];
        }

        // --- P (D-layout) -> plds (A-layout source), swizzled ---
        unsigned short* pw = plds[wave];
        #pragma unroll
        for (int ct = 0; ct < 4; ++ct) {
            #pragma unroll
            for (int i = 0; i < 4; ++i) {
                const int row = grp * 4 + i;
                const int col = ct * 16 + l16;
                pw[row * 64 + (col ^ ((row & 7) << 3))] = pb[ct][i];
            }
        }

        // --- PV: O[16 x 64] += P[16 x 64] * V[64 x 64] ---
        #pragma unroll
        for (int kk = 0; kk < 2; ++kk) {
            const int psw = (l16 & 7) << 3;
            short8 pa = *(const short8*)&pw[l16 * 64 + ((kk * 32 + grp * 8) ^ psw)];
            #pragma unroll
            for (int dt = 0; dt < 4; ++dt) {
                const int vrow = dt * 16 + l16;
                short8 vb = *(const short8*)&vlds[vrow * 64 + ((kk * 32 + grp * 8) ^ ((vrow & 7) << 3))];
                o_acc[dt] = __builtin_amdgcn_mfma_f32_16x16x32_bf16(pa, vb, o_acc[dt], 0, 0, 0);
            }
        }
    }

    // --- epilogue: normalize and store ---
    #pragma unroll
    for (int i = 0; i < 4; ++i) {
        const float inv = 1.0f / l_r[i];
        const int row = qt * QBLK + wave * 16 + grp * 4 + i;
        float* orow = op + (size_t)row * C_;
        #pragma unroll
        for (int dt = 0; dt < 4; ++dt)
            orow[dt * 16 + l16] = o_acc[dt][i] * inv;
    }
}

extern "C" void kernel_launch(void* const* d_in, const int* in_sizes, int n_in,
                              void* d_out, int out_size, void* d_ws, size_t ws_size,
                              hipStream_t stream) {
    const float* q = (const float*)d_in[0];
    const float* k = (const float*)d_in[1];
    const float* v = (const float*)d_in[2];
    float* o = (float*)d_out;
    dim3 grid(B_ * H_ * (N_ / QBLK));  // 2048 blocks
    dim3 block(256);
    attn_fwd<<<grid, block, 0, stream>>>(q, k, v, o);
}

// Round 2
// 151.595 us; speedup vs baseline: 1.8845x; 1.8845x over previous
//
#include <hip/hip_runtime.h>
#include <hip/hip_bf16.h>

#define B_   4
#define N_   2048
#define C_   1024
#define NT   32
#define QSCALE 0.18033688011112042f   // 0.125 * log2(e)

typedef __attribute__((ext_vector_type(8))) short short8;
typedef __attribute__((ext_vector_type(4))) short short4v;
typedef __attribute__((ext_vector_type(4))) float f32x4;

__device__ __forceinline__ unsigned short f2bf(float x) {
    union { __hip_bfloat16 h; unsigned short u; } c;
    c.h = __float2bfloat16(x);   // RNE
    return c.u;
}

// ---- pre-pass: f32 [B,N,C] -> bf16 tiled pre-swizzled K [kv][d] and V^T [d][kv] ----
__global__ __launch_bounds__(256) void prepack(
    const float* __restrict__ K, const float* __restrict__ V,
    unsigned short* __restrict__ Kt, unsigned short* __restrict__ Vt)
{
    __shared__ __align__(16) unsigned short vl[64 * 64];
    const int blk = blockIdx.x;            // head*32 + tile
    const int t = blk & 31, head = blk >> 5;
    const int b = head >> 4, h = head & 15;
    const int tid = threadIdx.x;
    const int r = tid >> 2, cb = tid & 3;  // r: 0..63 row, cb: 16-elem col block
    const size_t head_off = (size_t)b * N_ * C_ + (size_t)h * 64;
    const int kv0 = t * 64;

    // K tile -> swizzled bf16 image [kv][d]
    {
        const float* src = K + head_off + (size_t)(kv0 + r) * C_ + cb * 16;
        f32x4 x0 = *(const f32x4*)(src);
        f32x4 x1 = *(const f32x4*)(src + 4);
        f32x4 x2 = *(const f32x4*)(src + 8);
        f32x4 x3 = *(const f32x4*)(src + 12);
        short8 p0, p1;
        #pragma unroll
        for (int i = 0; i < 4; ++i) {
            p0[i] = (short)f2bf(x0[i]); p0[i + 4] = (short)f2bf(x1[i]);
            p1[i] = (short)f2bf(x2[i]); p1[i + 4] = (short)f2bf(x3[i]);
        }
        unsigned short* dst = Kt + (size_t)blk * 4096 + r * 64;
        const int swz = (r & 7) << 3;
        *(short8*)&dst[(cb * 16) ^ swz]     = p0;
        *(short8*)&dst[(cb * 16 + 8) ^ swz] = p1;
    }
    // V tile: transpose via LDS -> swizzled bf16 image [d][kv]
    {
        const float* src = V + head_off + (size_t)(kv0 + r) * C_ + cb * 16;
        f32x4 y0 = *(const f32x4*)(src);
        f32x4 y1 = *(const f32x4*)(src + 4);
        f32x4 y2 = *(const f32x4*)(src + 8);
        f32x4 y3 = *(const f32x4*)(src + 12);
        #pragma unroll
        for (int i = 0; i < 4; ++i) {
            vl[(cb * 16 + i) * 64 + r]      = f2bf(y0[i]);
            vl[(cb * 16 + 4 + i) * 64 + r]  = f2bf(y1[i]);
            vl[(cb * 16 + 8 + i) * 64 + r]  = f2bf(y2[i]);
            vl[(cb * 16 + 12 + i) * 64 + r] = f2bf(y3[i]);
        }
    }
    __syncthreads();
    {
        short8 q0 = *(const short8*)&vl[r * 64 + cb * 16];
        short8 q1 = *(const short8*)&vl[r * 64 + cb * 16 + 8];
        unsigned short* dst = Vt + (size_t)blk * 4096 + r * 64;
        const int swz = (r & 7) << 3;
        *(short8*)&dst[(cb * 16) ^ swz]     = q0;
        *(short8*)&dst[(cb * 16 + 8) ^ swz] = q1;
    }
}

// ---- main attention kernel ----
__global__ __launch_bounds__(256, 4) void attn_fwd(
    const float* __restrict__ Q, const unsigned short* __restrict__ Kt,
    const unsigned short* __restrict__ Vt, float* __restrict__ O)
{
    __shared__ __align__(16) unsigned short klds[2][4096];
    __shared__ __align__(16) unsigned short vlds[2][4096];
    __shared__ __align__(16) unsigned short plds[4][1024];

    const int L = blockIdx.x;
    const int xcd = L & 7;
    const int j = L >> 3;
    const int head = xcd + 8 * (j >> 5);   // all 32 q-tiles of a head on one XCD
    const int qt = j & 31;
    const int b = head >> 4, h = head & 15;

    const int tid  = threadIdx.x;
    const int wave = tid >> 6;
    const int lane = tid & 63;
    const int l16  = lane & 15;
    const int grp  = lane >> 4;

    const unsigned short* kbase = Kt + (size_t)head * (NT * 4096);
    const unsigned short* vbase = Vt + (size_t)head * (NT * 4096);
    const float* qp = Q + (size_t)b * N_ * C_ + (size_t)h * 64;
    float*       op = O + (size_t)b * N_ * C_ + (size_t)h * 64;

    // Q fragment (rows qt*64 + wave*16 + l16), scale*log2e folded
    const int qrow = qt * 64 + wave * 16 + l16;
    short8 qa[2];
    {
        const float* qr = qp + (size_t)qrow * C_ + grp * 8;
        #pragma unroll
        for (int kk = 0; kk < 2; ++kk) {
            f32x4 x0 = *(const f32x4*)(qr + kk * 32);
            f32x4 x1 = *(const f32x4*)(qr + kk * 32 + 4);
            short8 a;
            #pragma unroll
            for (int i = 0; i < 4; ++i) {
                a[i]     = (short)f2bf(x0[i] * QSCALE);
                a[i + 4] = (short)f2bf(x1[i] * QSCALE);
            }
            qa[kk] = a;
        }
    }

    f32x4 o_acc[4] = {};
    float m_r = -3.0e38f, l_r = 0.0f;

    unsigned short* pw = plds[wave];
    const int psw = (l16 & 7) << 3;

    auto stage = [&](int t, int buf) {
        const unsigned short* kg = kbase + (size_t)t * 4096 + wave * 512 + lane * 8;
        const unsigned short* vg = vbase + (size_t)t * 4096 + wave * 512 + lane * 8;
        __builtin_amdgcn_global_load_lds((const __attribute__((address_space(1))) void*)kg,
            (__attribute__((address_space(3))) void*)&klds[buf][wave * 512], 16, 0, 0);
        __builtin_amdgcn_global_load_lds((const __attribute__((address_space(1))) void*)(kg + 2048),
            (__attribute__((address_space(3))) void*)&klds[buf][2048 + wave * 512], 16, 0, 0);
        __builtin_amdgcn_global_load_lds((const __attribute__((address_space(1))) void*)vg,
            (__attribute__((address_space(3))) void*)&vlds[buf][wave * 512], 16, 0, 0);
        __builtin_amdgcn_global_load_lds((const __attribute__((address_space(1))) void*)(vg + 2048),
            (__attribute__((address_space(3))) void*)&vlds[buf][2048 + wave * 512], 16, 0, 0);
    };

    stage(0, 0);
    int cur = 0;

    for (int t = 0; t < NT; ++t) {
        asm volatile("s_waitcnt vmcnt(0)" ::: "memory");
        __syncthreads();
        if (t + 1 < NT) stage(t + 1, cur ^ 1);   // prefetch overlaps compute below

        const unsigned short* kl = klds[cur];
        const unsigned short* vl = vlds[cur];

        // QK^T swapped: s = mfma(K, Q) -> lane holds q = l16, kv = ct*16 + grp*4 + i
        f32x4 s[4];
        #pragma unroll
        for (int ct = 0; ct < 4; ++ct) {
            const int krow = ct * 16 + l16;
            const int ksw  = (krow & 7) << 3;
            short8 k0 = *(const short8*)&kl[krow * 64 + ((grp * 8) ^ ksw)];
            short8 k1 = *(const short8*)&kl[krow * 64 + ((32 + grp * 8) ^ ksw)];
            f32x4 acc = {};
            acc = __builtin_amdgcn_mfma_f32_16x16x32_bf16(k0, qa[0], acc, 0, 0, 0);
            acc = __builtin_amdgcn_mfma_f32_16x16x32_bf16(k1, qa[1], acc, 0, 0, 0);
            s[ct] = acc;
        }

        // online softmax, exp2 domain; row stats live in lanes keyed by l16
        float vm = fmaxf(fmaxf(s[0][0], s[0][1]), fmaxf(s[0][2], s[0][3]));
        #pragma unroll
        for (int ct = 1; ct < 4; ++ct)
            vm = fmaxf(vm, fmaxf(fmaxf(s[ct][0], s[ct][1]), fmaxf(s[ct][2], s[ct][3])));
        vm = fmaxf(vm, __shfl_xor(vm, 16));
        vm = fmaxf(vm, __shfl_xor(vm, 32));

        if (!__all(vm - m_r <= 8.0f)) {          // T13 defer-max
            const float mnew = fmaxf(m_r, vm);
            const float corr = exp2f(m_r - mnew);
            m_r = mnew;
            l_r *= corr;
            #pragma unroll
            for (int i = 0; i < 4; ++i) {
                const float ci = __shfl(corr, grp * 4 + i);
                #pragma unroll
                for (int dt = 0; dt < 4; ++dt) o_acc[dt][i] *= ci;
            }
        }

        float rs = 0.0f;
        #pragma unroll
        for (int ct = 0; ct < 4; ++ct) {
            const float p0 = exp2f(s[ct][0] - m_r);
            const float p1 = exp2f(s[ct][1] - m_r);
            const float p2 = exp2f(s[ct][2] - m_r);
            const float p3 = exp2f(s[ct][3] - m_r);
            rs += (p0 + p1) + (p2 + p3);
            short4v w;
            w[0] = (short)f2bf(p0); w[1] = (short)f2bf(p1);
            w[2] = (short)f2bf(p2); w[3] = (short)f2bf(p3);
            *(short4v*)&pw[l16 * 64 + ((ct * 16 + grp * 4) ^ psw)] = w;  // b64 store
        }
        rs += __shfl_xor(rs, 16);
        rs += __shfl_xor(rs, 32);
        l_r += rs;

        // PV: O[q][d] += P[q][kv] * V[kv][d]
        #pragma unroll
        for (int kk = 0; kk < 2; ++kk) {
            short8 pa = *(const short8*)&pw[l16 * 64 + ((kk * 32 + grp * 8) ^ psw)];
            #pragma unroll
            for (int dt = 0; dt < 4; ++dt) {
                const int vrow = dt * 16 + l16;
                short8 vb = *(const short8*)&vl[vrow * 64 + ((kk * 32 + grp * 8) ^ ((vrow & 7) << 3))];
                o_acc[dt] = __builtin_amdgcn_mfma_f32_16x16x32_bf16(pa, vb, o_acc[dt], 0, 0, 0);
            }
        }
        cur ^= 1;
    }

    const float inv = 1.0f / l_r;
    #pragma unroll
    for (int i = 0; i < 4; ++i) {
        const float vi = __shfl(inv, grp * 4 + i);
        float* orow = op + (size_t)(qt * 64 + wave * 16 + grp * 4 + i) * C_;
        #pragma unroll
        for (int dt = 0; dt < 4; ++dt)
            orow[dt * 16 + l16] = o_acc[dt][i] * vi;
    }
}

extern "C" void kernel_launch(void* const* d_in, const int* in_sizes, int n_in,
                              void* d_out, int out_size, void* d_ws, size_t ws_size,
                              hipStream_t stream) {
    const float* q = (const float*)d_in[0];
    const float* k = (const float*)d_in[1];
    const float* v = (const float*)d_in[2];
    float* o = (float*)d_out;
    unsigned short* Kt = (unsigned short*)d_ws;                 // 16 MB
    unsigned short* Vt = Kt + (size_t)64 * NT * 4096;           // +16 MB
    prepack<<<dim3(64 * NT), dim3(256), 0, stream>>>(k, v, Kt, Vt);
    attn_fwd<<<dim3(64 * NT), dim3(256), 0, stream>>>(q, Kt, Vt, o);
}

// Round 3
// 115.047 us; speedup vs baseline: 2.4831x; 1.3177x over previous
//
#include <hip/hip_runtime.h>
#include <hip/hip_bf16.h>

#define B_   4
#define N_   2048
#define C_   1024
#define NT   32
#define QSCALE 0.18033688011112042f   // 0.125 * log2(e)

typedef __attribute__((ext_vector_type(8)))  short short8;
typedef __attribute__((ext_vector_type(4)))  float f32x4;
typedef __attribute__((ext_vector_type(16))) float f32x16;
typedef __attribute__((ext_vector_type(2)))  int   int2v;

__device__ __forceinline__ unsigned short f2bf(float x) {
    union { __hip_bfloat16 h; unsigned short u; } c;
    c.h = __float2bfloat16(x);
    return c.u;
}
__device__ __forceinline__ float fast_exp2(float x) {
    float r; asm("v_exp_f32 %0, %1" : "=v"(r) : "v"(x)); return r;
}
__device__ __forceinline__ int cvtpk(float a, float b) {
    int r; asm("v_cvt_pk_bf16_f32 %0, %1, %2" : "=v"(r) : "v"(a), "v"(b)); return r;
}

// ---- pre-pass: f32 [B,N,C] -> bf16 tiled pre-swizzled K [kv][d] and V^T [d][kv] ----
__global__ __launch_bounds__(256) void prepack(
    const float* __restrict__ K, const float* __restrict__ V,
    unsigned short* __restrict__ Kt, unsigned short* __restrict__ Vt)
{
    __shared__ __align__(16) unsigned short vl[64 * 64];
    const int blk = blockIdx.x;            // head*32 + tile
    const int t = blk & 31, head = blk >> 5;
    const int b = head >> 4, h = head & 15;
    const int tid = threadIdx.x;
    const int r = tid >> 2, cb = tid & 3;
    const size_t head_off = (size_t)b * N_ * C_ + (size_t)h * 64;
    const int kv0 = t * 64;

    {
        const float* src = K + head_off + (size_t)(kv0 + r) * C_ + cb * 16;
        f32x4 x0 = *(const f32x4*)(src);
        f32x4 x1 = *(const f32x4*)(src + 4);
        f32x4 x2 = *(const f32x4*)(src + 8);
        f32x4 x3 = *(const f32x4*)(src + 12);
        short8 p0, p1;
        #pragma unroll
        for (int i = 0; i < 4; ++i) {
            p0[i] = (short)f2bf(x0[i]); p0[i + 4] = (short)f2bf(x1[i]);
            p1[i] = (short)f2bf(x2[i]); p1[i + 4] = (short)f2bf(x3[i]);
        }
        unsigned short* dst = Kt + (size_t)blk * 4096 + r * 64;
        const int swz = (r & 7) << 3;
        *(short8*)&dst[(cb * 16) ^ swz]     = p0;
        *(short8*)&dst[(cb * 16 + 8) ^ swz] = p1;
    }
    {
        const float* src = V + head_off + (size_t)(kv0 + r) * C_ + cb * 16;
        f32x4 y0 = *(const f32x4*)(src);
        f32x4 y1 = *(const f32x4*)(src + 4);
        f32x4 y2 = *(const f32x4*)(src + 8);
        f32x4 y3 = *(const f32x4*)(src + 12);
        #pragma unroll
        for (int i = 0; i < 4; ++i) {
            vl[(cb * 16 + i) * 64 + r]      = f2bf(y0[i]);
            vl[(cb * 16 + 4 + i) * 64 + r]  = f2bf(y1[i]);
            vl[(cb * 16 + 8 + i) * 64 + r]  = f2bf(y2[i]);
            vl[(cb * 16 + 12 + i) * 64 + r] = f2bf(y3[i]);
        }
    }
    __syncthreads();
    {
        short8 q0 = *(const short8*)&vl[r * 64 + cb * 16];
        short8 q1 = *(const short8*)&vl[r * 64 + cb * 16 + 8];
        unsigned short* dst = Vt + (size_t)blk * 4096 + r * 64;
        const int swz = (r & 7) << 3;
        *(short8*)&dst[(cb * 16) ^ swz]     = q0;
        *(short8*)&dst[(cb * 16 + 8) ^ swz] = q1;
    }
}

// ---- main attention: 4 waves x 32 q-rows, 32x32x16 MFMA, in-register softmax ----
__global__ __launch_bounds__(256, 4) void attn_fwd(
    const float* __restrict__ Q, const unsigned short* __restrict__ Kt,
    const unsigned short* __restrict__ Vt, float* __restrict__ O)
{
    __shared__ __align__(16) unsigned short klds[2][4096];
    __shared__ __align__(16) unsigned short vlds[2][4096];

    const int L = blockIdx.x;              // 1024 blocks
    const int xcd = L & 7;
    const int j = L >> 3;                  // 0..127
    const int head = xcd + 8 * (j >> 4);   // all 16 q-blocks of a head on one XCD
    const int qt = j & 15;
    const int b = head >> 4, h = head & 15;

    const int tid  = threadIdx.x;
    const int wave = tid >> 6;
    const int lane = tid & 63;
    const int l31  = lane & 31;
    const int hi   = lane >> 5;
    const int sw8  = (l31 & 7) << 3;

    const unsigned short* kbase = Kt + (size_t)head * (NT * 4096);
    const unsigned short* vbase = Vt + (size_t)head * (NT * 4096);
    const float* qp = Q + (size_t)b * N_ * C_ + (size_t)h * 64;
    float*       op = O + (size_t)b * N_ * C_ + (size_t)h * 64;

    // Q B-fragments: row q = qt*128 + wave*32 + l31, k = ks*16 + hi*8 + j
    const int qrow = qt * 128 + wave * 32 + l31;
    short8 qfrag[4];
    {
        const float* qr = qp + (size_t)qrow * C_ + hi * 8;
        #pragma unroll
        for (int ks = 0; ks < 4; ++ks) {
            f32x4 x0 = *(const f32x4*)(qr + ks * 16);
            f32x4 x1 = *(const f32x4*)(qr + ks * 16 + 4);
            short8 a;
            #pragma unroll
            for (int i = 0; i < 4; ++i) {
                a[i]     = (short)f2bf(x0[i] * QSCALE);
                a[i + 4] = (short)f2bf(x1[i] * QSCALE);
            }
            qfrag[ks] = a;
        }
    }

    f32x16 o0 = {}, o1 = {};
    float m_r = -3.0e38f, l_r = 0.0f;

    auto stage = [&](int t, int buf) {
        const unsigned short* kg = kbase + (size_t)t * 4096 + wave * 512 + lane * 8;
        const unsigned short* vg = vbase + (size_t)t * 4096 + wave * 512 + lane * 8;
        __builtin_amdgcn_global_load_lds((const __attribute__((address_space(1))) void*)kg,
            (__attribute__((address_space(3))) void*)&klds[buf][wave * 512], 16, 0, 0);
        __builtin_amdgcn_global_load_lds((const __attribute__((address_space(1))) void*)(kg + 2048),
            (__attribute__((address_space(3))) void*)&klds[buf][2048 + wave * 512], 16, 0, 0);
        __builtin_amdgcn_global_load_lds((const __attribute__((address_space(1))) void*)vg,
            (__attribute__((address_space(3))) void*)&vlds[buf][wave * 512], 16, 0, 0);
        __builtin_amdgcn_global_load_lds((const __attribute__((address_space(1))) void*)(vg + 2048),
            (__attribute__((address_space(3))) void*)&vlds[buf][2048 + wave * 512], 16, 0, 0);
    };

    stage(0, 0);
    int cur = 0;

    for (int t = 0; t < NT; ++t) {
        asm volatile("s_waitcnt vmcnt(0)" ::: "memory");
        __syncthreads();
        if (t + 1 < NT) stage(t + 1, cur ^ 1);

        const unsigned short* kl = klds[cur];
        const unsigned short* vl = vlds[cur];

        // --- QK^T swapped: S^T[kv][q]; lane: q = l31, kv per reg ---
        f32x16 s0 = {}, s1 = {};
        __builtin_amdgcn_s_setprio(1);
        #pragma unroll
        for (int ks = 0; ks < 4; ++ks) {
            const int cofs = (ks * 16 + hi * 8) ^ sw8;
            short8 kf0 = *(const short8*)&kl[l31 * 64 + cofs];
            short8 kf1 = *(const short8*)&kl[(32 + l31) * 64 + cofs];
            s0 = __builtin_amdgcn_mfma_f32_32x32x16_bf16(kf0, qfrag[ks], s0, 0, 0, 0);
            s1 = __builtin_amdgcn_mfma_f32_32x32x16_bf16(kf1, qfrag[ks], s1, 0, 0, 0);
        }
        __builtin_amdgcn_s_setprio(0);

        // --- in-lane max over 32 scores, then cross-half via permlane32_swap ---
        float mx[16];
        #pragma unroll
        for (int r = 0; r < 16; ++r) mx[r] = fmaxf(s0[r], s1[r]);
        #pragma unroll
        for (int st = 8; st; st >>= 1) {
            #pragma unroll
            for (int r = 0; r < st; ++r) mx[r] = fmaxf(mx[r], mx[r + st]);
        }
        int2v msw = __builtin_amdgcn_permlane32_swap(__float_as_int(mx[0]), __float_as_int(mx[0]), false, false);
        const float rm = fmaxf(__int_as_float(msw[0]), __int_as_float(msw[1]));

        if (!__all(rm - m_r <= 8.0f)) {      // T13 defer-max
            const float mnew = fmaxf(m_r, rm);
            const float corr = fast_exp2(m_r - mnew);
            m_r = mnew;
            l_r *= corr;
            #pragma unroll
            for (int r = 0; r < 16; ++r) { o0[r] *= corr; o1[r] *= corr; }
        }

        // --- P = exp2(S - m), in place ---
        #pragma unroll
        for (int r = 0; r < 16; ++r) {
            s0[r] = fast_exp2(s0[r] - m_r);
            s1[r] = fast_exp2(s1[r] - m_r);
        }
        // row sum
        float aa[16];
        #pragma unroll
        for (int r = 0; r < 16; ++r) aa[r] = s0[r] + s1[r];
        #pragma unroll
        for (int st = 8; st; st >>= 1) {
            #pragma unroll
            for (int r = 0; r < st; ++r) aa[r] += aa[r + st];
        }
        int2v ssw = __builtin_amdgcn_permlane32_swap(__float_as_int(aa[0]), __float_as_int(aa[0]), false, false);
        l_r += __int_as_float(ssw[0]) + __int_as_float(ssw[1]);

        // --- T12: P -> bf16 PV B-fragments via cvt_pk + permlane32_swap ---
        short8 pf[4];
        #pragma unroll
        for (int ct = 0; ct < 2; ++ct) {
            #pragma unroll
            for (int kss = 0; kss < 2; ++kss) {
                float e0, e1, e2, e3, e4, e5, e6, e7;
                if (ct == 0) {
                    e0 = s0[8*kss+0]; e1 = s0[8*kss+1]; e2 = s0[8*kss+2]; e3 = s0[8*kss+3];
                    e4 = s0[8*kss+4]; e5 = s0[8*kss+5]; e6 = s0[8*kss+6]; e7 = s0[8*kss+7];
                } else {
                    e0 = s1[8*kss+0]; e1 = s1[8*kss+1]; e2 = s1[8*kss+2]; e3 = s1[8*kss+3];
                    e4 = s1[8*kss+4]; e5 = s1[8*kss+5]; e6 = s1[8*kss+6]; e7 = s1[8*kss+7];
                }
                int w0 = cvtpk(e0, e1);
                int w1 = cvtpk(e2, e3);
                int w2 = cvtpk(e4, e5);
                int w3 = cvtpk(e6, e7);
                int2v sA = __builtin_amdgcn_permlane32_swap(w0, w2, false, false);
                int2v sB = __builtin_amdgcn_permlane32_swap(w1, w3, false, false);
                union { int i[4]; short8 v; } u;
                u.i[0] = sA[0]; u.i[1] = sB[0]; u.i[2] = sA[1]; u.i[3] = sB[1];
                pf[ct * 2 + kss] = u.v;
            }
        }

        // --- PV swapped: O^T[d][q] += V^T[d][kv] * P^T[kv][q] ---
        __builtin_amdgcn_s_setprio(1);
        #pragma unroll
        for (int ks = 0; ks < 4; ++ks) {
            const int cofs = (ks * 16 + hi * 8) ^ sw8;
            short8 vf0 = *(const short8*)&vl[l31 * 64 + cofs];
            short8 vf1 = *(const short8*)&vl[(32 + l31) * 64 + cofs];
            o0 = __builtin_amdgcn_mfma_f32_32x32x16_bf16(vf0, pf[ks], o0, 0, 0, 0);
            o1 = __builtin_amdgcn_mfma_f32_32x32x16_bf16(vf1, pf[ks], o1, 0, 0, 0);
        }
        __builtin_amdgcn_s_setprio(0);

        cur ^= 1;
    }

    // --- epilogue: normalize (per-lane) and store; lane owns row q = qrow ---
    const float inv = 1.0f / l_r;
    float* orow = op + (size_t)qrow * C_;
    #pragma unroll
    for (int bb = 0; bb < 4; ++bb) {
        f32x4 w0, w1;
        #pragma unroll
        for (int i = 0; i < 4; ++i) {
            w0[i] = o0[4 * bb + i] * inv;
            w1[i] = o1[4 * bb + i] * inv;
        }
        *(f32x4*)(orow + 8 * bb + 4 * hi)      = w0;   // d = bb*8 + hi*4 + i
        *(f32x4*)(orow + 32 + 8 * bb + 4 * hi) = w1;
    }
}

extern "C" void kernel_launch(void* const* d_in, const int* in_sizes, int n_in,
                              void* d_out, int out_size, void* d_ws, size_t ws_size,
                              hipStream_t stream) {
    const float* q = (const float*)d_in[0];
    const float* k = (const float*)d_in[1];
    const float* v = (const float*)d_in[2];
    float* o = (float*)d_out;
    unsigned short* Kt = (unsigned short*)d_ws;                 // 16 MB
    unsigned short* Vt = Kt + (size_t)64 * NT * 4096;           // +16 MB
    prepack<<<dim3(64 * NT), dim3(256), 0, stream>>>(k, v, Kt, Vt);
    attn_fwd<<<dim3(1024), dim3(256), 0, stream>>>(q, Kt, Vt, o);
}